// Round 3
// baseline (2285.835 us; speedup 1.0000x reference)
//
#include <hip/hip_runtime.h>

#define HW 16384
#define CH 256

// ---------------- depthwise 3x3, pad 1, per-channel ----------------
// grid: B*256 blocks (one (b,c) plane), 256 threads
__global__ __launch_bounds__(256) void k_dw(const float* __restrict__ in,
                                            const float* __restrict__ w,
                                            float* __restrict__ out) {
  int bc = blockIdx.x;
  int c = bc & 255;
  float wv[9];
#pragma unroll
  for (int i = 0; i < 9; ++i) wv[i] = w[c * 9 + i];
  const float* ip = in + (size_t)bc * HW;
  float* op = out + (size_t)bc * HW;
  int t = threadIdx.x;
  for (int r = 0; r < 64; ++r) {
    int pix = r * 256 + t;
    int y = pix >> 7, x = pix & 127;
    float s = 0.f;
#pragma unroll
    for (int dy = 0; dy < 3; ++dy) {
      int yy = y + dy - 1;
      if (yy < 0 || yy > 127) continue;
#pragma unroll
      for (int dx = 0; dx < 3; ++dx) {
        int xx = x + dx - 1;
        if (xx < 0 || xx > 127) continue;
        s += wv[dy * 3 + dx] * ip[yy * 128 + xx];
      }
    }
    op[pix] = s;
  }
}

// ---------------- pointwise 1x1 as GEMM ----------------
// out[b][m][n] = sum_k Wt[m][k] * T[b][k][n]; 64x64 tile, BK=16
__global__ __launch_bounds__(256) void k_pw(const float* __restrict__ T,
                                            const float* __restrict__ Wt,
                                            float* __restrict__ out) {
  __shared__ float As[16][64];
  __shared__ float Bs[16][64];
  int b = blockIdx.z;
  int m0 = blockIdx.y * 64, n0 = blockIdx.x * 64;
  const float* Tb = T + (size_t)b * CH * HW;
  int t = threadIdx.x, ty = t >> 4, tx = t & 15;
  int am = t >> 2, ak = (t & 3) * 4;
  int bk = t >> 4, bn = (t & 15) * 4;
  float acc[4][4] = {};
  for (int k0 = 0; k0 < 256; k0 += 16) {
    float4 a4 = *(const float4*)(Wt + (size_t)(m0 + am) * 256 + k0 + ak);
    As[ak + 0][am] = a4.x; As[ak + 1][am] = a4.y;
    As[ak + 2][am] = a4.z; As[ak + 3][am] = a4.w;
    *(float4*)&Bs[bk][bn] = *(const float4*)(Tb + (size_t)(k0 + bk) * HW + n0 + bn);
    __syncthreads();
#pragma unroll
    for (int kk = 0; kk < 16; ++kk) {
      float4 a = *(const float4*)&As[kk][ty * 4];
      float4 bv = *(const float4*)&Bs[kk][tx * 4];
      float av[4] = {a.x, a.y, a.z, a.w};
      float bvv[4] = {bv.x, bv.y, bv.z, bv.w};
#pragma unroll
      for (int i = 0; i < 4; ++i)
#pragma unroll
        for (int j = 0; j < 4; ++j) acc[i][j] += av[i] * bvv[j];
    }
    __syncthreads();
  }
#pragma unroll
  for (int i = 0; i < 4; ++i) {
    float4 o;
    o.x = acc[i][0]; o.y = acc[i][1]; o.z = acc[i][2]; o.w = acc[i][3];
    *(float4*)(out + ((size_t)b * CH + m0 + ty * 4 + i) * HW + n0 + tx * 4) = o;
  }
}

// ---------------- 8x8 max pool + head rearrange ----------------
// src: [B][256][HW] -> dst: [B*4][256 cells][64 dh]; channel c = dh*4 + head
__global__ __launch_bounds__(256) void k_pool(const float* __restrict__ src,
                                              float* __restrict__ dst) {
  int idx = blockIdx.x * 256 + threadIdx.x;
  int cell = idx & 255;
  int c = (idx >> 8) & 255;
  int b = idx >> 16;
  int sy = cell >> 4, sx = cell & 15;
  const float* sp = src + ((size_t)b * CH + c) * HW + (sy * 8) * 128 + sx * 8;
  float m = -1e30f;
#pragma unroll
  for (int iy = 0; iy < 8; ++iy) {
    float4 v0 = *(const float4*)(sp + iy * 128);
    float4 v1 = *(const float4*)(sp + iy * 128 + 4);
    m = fmaxf(m, fmaxf(fmaxf(v0.x, v0.y), fmaxf(v0.z, v0.w)));
    m = fmaxf(m, fmaxf(fmaxf(v1.x, v1.y), fmaxf(v1.z, v1.w)));
  }
  int dh = c >> 2, head = c & 3;
  dst[((size_t)(b * 4 + head) * 256 + cell) * 64 + dh] = m;
}

// ---------------- attention ----------------
// q: [B][256][HW] planar (ch = dh*4+head); kp,vp: [B*4][256 cells][64 dh]
// attn_o: [B*4][HW][256] f32; ao: [B][256][HW] (ch = dh*4+head)
// grid (256,4,4), 256 thr; thread (p=t>>2, g=t&3); per 64-key chunk c,
// thread owns keys j = c*64 + g*16 + ii, ii in [0,16).
__global__ __launch_bounds__(256, 2) void k_attn(
    const float* __restrict__ q, const float* __restrict__ kp,
    const float* __restrict__ vp, const float* __restrict__ relh,
    const float* __restrict__ relw, float* __restrict__ attn_o,
    float* __restrict__ ao) {
  int tile = blockIdx.x, head = blockIdx.y, b = blockIdx.z;
  int t = threadIdx.x;
  int p = t >> 2, g = t & 3;
  int pix0 = tile * 64;
  int pix = pix0 + p;
  int y = pix >> 7, x = pix & 127;

  // qs [0,16384) kv [16384,32768) relc [32768,48640) rhw [48640,56832)
  __shared__ __align__(16) char smem[56832];
  float* qs   = (float*)smem;
  float* kv   = (float*)(smem + 16384);
  float* relc = (float*)(smem + 32768);
  float* rhw  = (float*)(smem + 48640);

  // stage q tile: planar -> [pix][dh]
  {
    int dh = t >> 2;
    int po = (t & 3) * 16;
    const float* sp = q + ((size_t)b * CH + dh * 4 + head) * HW + pix0 + po;
#pragma unroll
    for (int u4 = 0; u4 < 4; ++u4) {
      float4 v = *(const float4*)(sp + u4 * 4);
      qs[(po + u4 * 4 + 0) * 64 + dh] = v.x;
      qs[(po + u4 * 4 + 1) * 64 + dh] = v.y;
      qs[(po + u4 * 4 + 2) * 64 + dh] = v.z;
      qs[(po + u4 * 4 + 3) * 64 + dh] = v.w;
    }
  }
  for (int e = t; e < 3968; e += 256)
    relc[e] = (e < 1984) ? relh[e] : relw[e - 1984];
  __syncthreads();

  float qr[64];
#pragma unroll
  for (int dv = 0; dv < 16; ++dv) {
    float4 v = *(const float4*)&qs[p * 64 + dv * 4];
    qr[dv * 4 + 0] = v.x; qr[dv * 4 + 1] = v.y;
    qr[dv * 4 + 2] = v.z; qr[dv * 4 + 3] = v.w;
  }

  // rel-pos: rhw[p][hk] = q.relh[hk - y/8 + 15]; rhw[p][16+wk] = q.relw[wk - x/8 + 15]
  {
    int ybase = 15 - (y >> 3);
    int xbase = 15 - (x >> 3);
#pragma unroll
    for (int mm = 0; mm < 8; ++mm) {
      int m = g * 8 + mm;
      int row = (m < 16) ? (m + ybase) : (m - 16 + xbase);
      const float* kr = &relc[((m < 16) ? 0 : 1984) + row * 64];
      float s = 0.f;
#pragma unroll
      for (int dv = 0; dv < 64; ++dv) s += qr[dv] * kr[dv];
      rhw[p * 32 + m] = s;
    }
  }

  // QK^T over 4 chunks of 64 keys
  float L[64];
  const size_t kvbase = (size_t)(b * 4 + head) * 256 * 64;
#pragma unroll
  for (int c = 0; c < 4; ++c) {
    __syncthreads();
    {
      int krow = t >> 2, doff = (t & 3) * 16;
      const float* sp = kp + kvbase + (size_t)(c * 64 + krow) * 64 + doff;
      float* dp = &kv[krow * 64 + doff];
#pragma unroll
      for (int u4 = 0; u4 < 4; ++u4)
        *(float4*)(dp + u4 * 4) = *(const float4*)(sp + u4 * 4);
    }
    __syncthreads();
#pragma unroll
    for (int ii = 0; ii < 16; ++ii) {
      const float* kk = &kv[(g * 16 + ii) * 64];
      float s = 0.f;
#pragma unroll
      for (int dv = 0; dv < 16; ++dv) {
        float4 k4 = *(const float4*)&kk[dv * 4];
        s += qr[dv * 4 + 0] * k4.x + qr[dv * 4 + 1] * k4.y +
             qr[dv * 4 + 2] * k4.z + qr[dv * 4 + 3] * k4.w;
      }
      L[c * 16 + ii] = s;
    }
  }

  // softmax (key j of L[i]: j = (i>>4)*64 + g*16 + (i&15); hk=j>>4, wk=j&15)
  const float* myr = &rhw[p * 32];
  float mx = -1e30f;
#pragma unroll
  for (int i = 0; i < 64; ++i) {
    float Lv = (L[i] + myr[(i >> 4) * 4 + g] + myr[16 + (i & 15)]) * 0.125f;
    L[i] = Lv;
    mx = fmaxf(mx, Lv);
  }
  mx = fmaxf(mx, __shfl_xor(mx, 1));
  mx = fmaxf(mx, __shfl_xor(mx, 2));
  float sum = 0.f;
#pragma unroll
  for (int i = 0; i < 64; ++i) {
    float e = __expf(L[i] - mx);
    L[i] = e; sum += e;
  }
  sum += __shfl_xor(sum, 1);
  sum += __shfl_xor(sum, 2);
  float inv = 1.f / sum;
#pragma unroll
  for (int i = 0; i < 64; ++i) L[i] *= inv;

  // write attn probs: thread's 16 keys per chunk are contiguous (64B lines)
  {
    float* arow = attn_o + ((size_t)(b * 4 + head) * HW + pix) * 256;
#pragma unroll
    for (int c = 0; c < 4; ++c) {
      float* dst = arow + c * 64 + g * 16;
#pragma unroll
      for (int u4 = 0; u4 < 4; ++u4) {
        float4 o;
        o.x = L[c * 16 + u4 * 4 + 0]; o.y = L[c * 16 + u4 * 4 + 1];
        o.z = L[c * 16 + u4 * 4 + 2]; o.w = L[c * 16 + u4 * 4 + 3];
        *(float4*)(dst + u4 * 4) = o;
      }
    }
  }

  // PV: partial over own keys for all 64 d, then quad butterfly reduce
  float acc[64];
#pragma unroll
  for (int d = 0; d < 64; ++d) acc[d] = 0.f;
  for (int c = 0; c < 4; ++c) {
    __syncthreads();
    {
      int krow = t >> 2, doff = (t & 3) * 16;
      const float* sp = vp + kvbase + (size_t)(c * 64 + krow) * 64 + doff;
      float* dp = &kv[krow * 64 + doff];
#pragma unroll
      for (int u4 = 0; u4 < 4; ++u4)
        *(float4*)(dp + u4 * 4) = *(const float4*)(sp + u4 * 4);
    }
    __syncthreads();
#pragma unroll
    for (int ii = 0; ii < 16; ++ii) {
      float a = L[c * 16 + ii];
      const float* vv = &kv[(g * 16 + ii) * 64];
#pragma unroll
      for (int dv = 0; dv < 16; ++dv) {
        float4 v4 = *(const float4*)&vv[dv * 4];
        acc[dv * 4 + 0] += a * v4.x; acc[dv * 4 + 1] += a * v4.y;
        acc[dv * 4 + 2] += a * v4.z; acc[dv * 4 + 3] += a * v4.w;
      }
    }
  }
#pragma unroll
  for (int d = 0; d < 64; ++d) {
    acc[d] += __shfl_xor(acc[d], 1);
    acc[d] += __shfl_xor(acc[d], 2);
  }
  {
    float* base = ao + (size_t)b * CH * HW + pix;
#pragma unroll
    for (int u = 0; u < 16; ++u) {
      int d = g * 16 + u;
      base[(size_t)(d * 4 + head) * HW] = acc[d];
    }
  }
}

extern "C" void kernel_launch(void* const* d_in, const int* in_sizes, int n_in,
                              void* d_out, int out_size, void* d_ws, size_t ws_size,
                              hipStream_t stream) {
  const float* x   = (const float*)d_in[0];
  const float* dw1 = (const float*)d_in[1];
  const float* pw1 = (const float*)d_in[2];
  const float* krw = (const float*)d_in[3];
  const float* krh = (const float*)d_in[4];
  const float* dw2 = (const float*)d_in[5];
  const float* pw2 = (const float*)d_in[6];

  float* out = (float*)d_out;                      // [B][256][HW], 16,777,216
  float* attnbuf = out + (size_t)16777216;         // [B*4][HW][256], 67,108,864

  // scratch inside d_out's attn region (dead until k_attn writes it):
  float* t1  = attnbuf;                            // dw1 out
  float* kvf = attnbuf + (size_t)16777216;         // k-full / v-full
  // d_ws (f32): q/t2 (16,777,216) + kp (262,144) + vp (262,144) = 69.2 MB
  float* qb = (float*)d_ws;
  float* kp = qb + (size_t)16777216;
  float* vp = kp + (size_t)262144;
  float* t2 = qb;                                  // reuse q region after attn

  dim3 b256(256);
  k_dw<<<dim3(1024), b256, 0, stream>>>(x, dw1, t1);
  k_pw<<<dim3(256, 4, 4), b256, 0, stream>>>(t1, pw1 + 65536, kvf);   // k
  k_pool<<<dim3(1024), b256, 0, stream>>>(kvf, kp);
  k_pw<<<dim3(256, 4, 4), b256, 0, stream>>>(t1, pw1 + 131072, kvf);  // v
  k_pool<<<dim3(1024), b256, 0, stream>>>(kvf, vp);
  k_pw<<<dim3(256, 4, 4), b256, 0, stream>>>(t1, pw1, qb);            // q
  k_attn<<<dim3(256, 4, 4), b256, 0, stream>>>(qb, kp, vp, krh, krw, attnbuf, out);
  k_dw<<<dim3(1024), b256, 0, stream>>>(out, dw2, t2);                // ao -> t2
  k_pw<<<dim3(256, 4, 4), b256, 0, stream>>>(t2, pw2, out);           // final
}